// Round 2
// baseline (932.395 us; speedup 1.0000x reference)
//
#include <hip/hip_runtime.h>

#define N 8192
#define F 128
#define NEWF 64
#define ALPHA 0.2f
#define TI 16

// ---------------------------------------------------------------------------
// Kernel 1: h = X @ W  (f32), s = h @ a_self, n = h @ a_neigh
// One wave per row; lane = output column k.
// ---------------------------------------------------------------------------
__global__ void k_hsn(const float* __restrict__ X, const float* __restrict__ W,
                      const float* __restrict__ a_self, const float* __restrict__ a_neigh,
                      float* __restrict__ h, float* __restrict__ s, float* __restrict__ n) {
    int row = blockIdx.x * 4 + (threadIdx.x >> 6);
    int l = threadIdx.x & 63;
    const float* xr = X + (size_t)row * F;
    float acc = 0.0f;
#pragma unroll 8
    for (int f = 0; f < F; ++f) acc += xr[f] * W[f * NEWF + l];
    h[(size_t)row * NEWF + l] = acc;
    float ts = acc * a_self[l];
    float tn = acc * a_neigh[l];
#pragma unroll
    for (int off = 32; off; off >>= 1) {
        ts += __shfl_xor(ts, off);
        tn += __shfl_xor(tn, off);
    }
    if (l == 0) { s[row] = ts; n[row] = tn; }
}

// ---------------------------------------------------------------------------
// Kernel 2: nmax = max_j n[j]  (single block)
// ---------------------------------------------------------------------------
__global__ void k_nmax(const float* __restrict__ n, float* __restrict__ nmax) {
    __shared__ float red[256];
    float m = -1e30f;
    for (int i = threadIdx.x; i < N; i += 256) m = fmaxf(m, n[i]);
    red[threadIdx.x] = m;
    __syncthreads();
    for (int off = 128; off; off >>= 1) {
        if ((int)threadIdx.x < off) red[threadIdx.x] = fmaxf(red[threadIdx.x], red[threadIdx.x + off]);
        __syncthreads();
    }
    if (threadIdx.x == 0) nmax[0] = red[0];
}

// ---------------------------------------------------------------------------
// Kernel 3: main fused attention.
//   Per block: TI=16 rows, 4 waves each own a contiguous j-quarter (2048 j).
//   Per 64-j chunk: prefetch next chunk's A (hide HBM latency under FMA),
//   e-phase (per-lane e computation -> LDS), FMA phase (uniform broadcast
//   ds_read_b128 of e + coalesced h row load + 16 FMAs per j).
//   Row-max bound M_i = leaky(s_i + nmax) -> single pass, no rescale,
//   A read exactly once.
// ---------------------------------------------------------------------------
__global__ void __launch_bounds__(256) k_main(
        const int* __restrict__ A, const float* __restrict__ h,
        const float* __restrict__ s, const float* __restrict__ n,
        const float* __restrict__ nmaxp, float* __restrict__ out) {
    __shared__ float ebuf[4][64][TI];   // [wave][j-in-chunk][ti]  (16 KB)
    __shared__ float zbuf[4][TI];

    int tid = threadIdx.x;
    int w = tid >> 6, l = tid & 63;
    int i0 = blockIdx.x * TI;
    float nmax = nmaxp[0];

    float sv[TI], Mv[TI], zv[TI], acc[TI];
#pragma unroll
    for (int ti = 0; ti < TI; ++ti) {
        float sval = s[i0 + ti];
        sv[ti] = sval;
        float t = sval + nmax;
        Mv[ti] = fmaxf(t, ALPHA * t);   // leaky_relu upper bound of the row max
        zv[ti] = 0.0f;
        acc[ti] = 0.0f;
    }

    const int jbeg = w * (N / 4);
    const int NC = (N / 4) / 64;        // 32 chunks per wave

    // ---- preload chunk 0's A into registers ----
    int av[TI];
#pragma unroll
    for (int ti = 0; ti < TI; ++ti) av[ti] = A[(size_t)(i0 + ti) * N + (jbeg + l)];

    for (int c = 0; c < NC; ++c) {
        const int jc = jbeg + c * 64;
        const int j = jc + l;
        const float nj = n[j];

        // ---- prefetch next chunk's A (drains under the FMA phase) ----
        int avn[TI];
        {
            int jn = (c + 1 < NC) ? (j + 64) : (jbeg + l);  // last iter: dummy reload
#pragma unroll
            for (int ti = 0; ti < TI; ++ti) avn[ti] = A[(size_t)(i0 + ti) * N + jn];
        }

        // ---- e-phase: each lane computes e for its j, all 16 rows ----
        float es[TI];
#pragma unroll
        for (int ti = 0; ti < TI; ++ti) {
            float t = sv[ti] + nj;
            float lv = fmaxf(t, ALPHA * t);           // leaky_relu
            float e = (av[ti] != 0) ? __expf(lv - Mv[ti]) : 0.0f;
            zv[ti] += e;
            es[ti] = e;
        }
        float4* dst = (float4*)&ebuf[w][l][0];
        dst[0] = make_float4(es[0], es[1], es[2], es[3]);
        dst[1] = make_float4(es[4], es[5], es[6], es[7]);
        dst[2] = make_float4(es[8], es[9], es[10], es[11]);
        dst[3] = make_float4(es[12], es[13], es[14], es[15]);
        // intra-wave producer->consumer: compiler orders ds ops via lgkmcnt

        // ---- FMA phase: broadcast e, coalesced h row, 16 FMAs per j ----
#pragma unroll 4
        for (int jj = 0; jj < 64; ++jj) {
            float hv = h[(size_t)(jc + jj) * NEWF + l];
            const float4* ep = (const float4*)&ebuf[w][jj][0];
            float4 e0 = ep[0], e1 = ep[1], e2 = ep[2], e3 = ep[3];
            acc[0]  += e0.x * hv;  acc[1]  += e0.y * hv;
            acc[2]  += e0.z * hv;  acc[3]  += e0.w * hv;
            acc[4]  += e1.x * hv;  acc[5]  += e1.y * hv;
            acc[6]  += e1.z * hv;  acc[7]  += e1.w * hv;
            acc[8]  += e2.x * hv;  acc[9]  += e2.y * hv;
            acc[10] += e2.z * hv;  acc[11] += e2.w * hv;
            acc[12] += e3.x * hv;  acc[13] += e3.y * hv;
            acc[14] += e3.z * hv;  acc[15] += e3.w * hv;
        }

#pragma unroll
        for (int ti = 0; ti < TI; ++ti) av[ti] = avn[ti];
    }

    // ---- finalize: reduce z across lanes, combine 4 waves via LDS ----
#pragma unroll
    for (int ti = 0; ti < TI; ++ti) {
        float z = zv[ti];
#pragma unroll
        for (int off = 32; off; off >>= 1) z += __shfl_xor(z, off);
        zv[ti] = z;
    }
    float (*abuf)[TI][64] = (float (*)[TI][64])ebuf;   // reuse 16 KB
#pragma unroll
    for (int ti = 0; ti < TI; ++ti) abuf[w][ti][l] = acc[ti];
    if (l == 0) {
#pragma unroll
        for (int ti = 0; ti < TI; ++ti) zbuf[w][ti] = zv[ti];
    }
    __syncthreads();

    int k = tid & 63;
    int g = tid >> 6;
#pragma unroll
    for (int r = 0; r < 4; ++r) {
        int ti = g * 4 + r;
        float sum = abuf[0][ti][k] + abuf[1][ti][k] + abuf[2][ti][k] + abuf[3][ti][k];
        float zz  = zbuf[0][ti] + zbuf[1][ti] + zbuf[2][ti] + zbuf[3][ti];
        out[(size_t)(i0 + ti) * NEWF + k] = fmaxf(sum / zz, 0.0f);
    }
}

// ---------------------------------------------------------------------------
extern "C" void kernel_launch(void* const* d_in, const int* in_sizes, int n_in,
                              void* d_out, int out_size, void* d_ws, size_t ws_size,
                              hipStream_t stream) {
    const float* X       = (const float*)d_in[0];
    const int*   A       = (const int*)d_in[1];
    const float* W       = (const float*)d_in[2];
    const float* a_self  = (const float*)d_in[3];
    const float* a_neigh = (const float*)d_in[4];
    float* out = (float*)d_out;

    float* wsf = (float*)d_ws;
    float* h    = wsf;                    // N*NEWF
    float* s    = h + (size_t)N * NEWF;   // N
    float* n    = s + N;                  // N
    float* nmax = n + N;                  // 1

    k_hsn<<<N / 4, 256, 0, stream>>>(X, W, a_self, a_neigh, h, s, n);
    k_nmax<<<1, 256, 0, stream>>>(n, nmax);
    k_main<<<N / TI, 256, 0, stream>>>(A, h, s, n, nmax, out);
}

// Round 3
// 545.911 us; speedup vs baseline: 1.7080x; 1.7080x over previous
//
#include <hip/hip_runtime.h>

#define N 8192
#define F 128
#define NEWF 64
#define ALPHA 0.2f

typedef float f32x4 __attribute__((ext_vector_type(4)));
typedef short short8 __attribute__((ext_vector_type(8)));

// ---------------------------------------------------------------------------
// Kernel 1: h = X @ W (f32), s = h @ a_self, n = h @ a_neigh
// ---------------------------------------------------------------------------
__global__ void k_hsn(const float* __restrict__ X, const float* __restrict__ W,
                      const float* __restrict__ a_self, const float* __restrict__ a_neigh,
                      float* __restrict__ h, float* __restrict__ s, float* __restrict__ n) {
    int row = blockIdx.x * 4 + (threadIdx.x >> 6);
    int l = threadIdx.x & 63;
    const float* xr = X + (size_t)row * F;
    float acc = 0.0f;
#pragma unroll 8
    for (int f = 0; f < F; ++f) acc += xr[f] * W[f * NEWF + l];
    h[(size_t)row * NEWF + l] = acc;
    float ts = acc * a_self[l];
    float tn = acc * a_neigh[l];
#pragma unroll
    for (int off = 32; off; off >>= 1) {
        ts += __shfl_xor(ts, off);
        tn += __shfl_xor(tn, off);
    }
    if (l == 0) { s[row] = ts; n[row] = tn; }
}

// ---------------------------------------------------------------------------
// Kernel 2: transpose h and split into bf16 hi/lo planes: hT[c][j]
// ---------------------------------------------------------------------------
__global__ void k_tr(const float* __restrict__ h, unsigned short* __restrict__ hThi,
                     unsigned short* __restrict__ hTlo) {
    __shared__ float tile[64][65];
    const int t = threadIdx.x;
    const int j0 = blockIdx.x * 64;
    {
        const int jr = t >> 2, cs = (t & 3) * 16;
        const float4* src = (const float4*)(h + (size_t)(j0 + jr) * NEWF + cs);
#pragma unroll
        for (int q = 0; q < 4; ++q) {
            float4 v = src[q];
            tile[jr][cs + q * 4 + 0] = v.x; tile[jr][cs + q * 4 + 1] = v.y;
            tile[jr][cs + q * 4 + 2] = v.z; tile[jr][cs + q * 4 + 3] = v.w;
        }
    }
    __syncthreads();
    {
        const int c = t >> 2, js = (t & 3) * 16;
        short8 hi0 = {}, hi1 = {}, lo0 = {}, lo1 = {};
#pragma unroll
        for (int k = 0; k < 16; ++k) {
            float v = tile[js + k][c];
            unsigned xb = __float_as_uint(v);
            short hb = (short)(xb >> 16);
            float lof = v - __uint_as_float(xb & 0xffff0000u);
            short lb = (short)(__float_as_uint(lof) >> 16);
            if (k < 8) { hi0[k] = hb; lo0[k] = lb; }
            else       { hi1[k - 8] = hb; lo1[k - 8] = lb; }
        }
        size_t off = (size_t)c * N + j0 + js;
        *(short8*)(hThi + off)     = hi0;
        *(short8*)(hThi + off + 8) = hi1;
        *(short8*)(hTlo + off)     = lo0;
        *(short8*)(hTlo + off + 8) = lo1;
    }
}

// ---------------------------------------------------------------------------
// Kernel 3: nmax = max_j n[j]
// ---------------------------------------------------------------------------
__global__ void k_nmax(const float* __restrict__ n, float* __restrict__ nmax) {
    __shared__ float red[1024];
    int t = threadIdx.x;
    float4 v0 = ((const float4*)n)[t];
    float4 v1 = ((const float4*)n)[t + 1024];
    float m = fmaxf(fmaxf(fmaxf(v0.x, v0.y), fmaxf(v0.z, v0.w)),
                    fmaxf(fmaxf(v1.x, v1.y), fmaxf(v1.z, v1.w)));
    red[t] = m;
    __syncthreads();
    for (int off = 512; off; off >>= 1) {
        if (t < off) red[t] = fmaxf(red[t], red[t + off]);
        __syncthreads();
    }
    if (t == 0) nmax[0] = red[0];
}

// ---------------------------------------------------------------------------
// Kernel 4: fused attention via split-bf16 MFMA.
//   Block = 512 threads (8 waves) x 16 rows. Wave w owns j in [w*1024, w*1024+1024).
//   Per K=32 chunk: lane l computes e for row l&15, k-slots (l>>4)*8+{0..7}
//   directly into the MFMA A-fragment (registers only). B-fragments come from
//   transposed bf16 hi/lo h planes (L2-resident, one b128 per fragment).
//   3-product split (hi*hi + hi*lo + lo*hi) keeps fp32-level accuracy.
//   Row-max bound M_i = leaky(s_i + nmax) -> single pass over A.
// ---------------------------------------------------------------------------
__global__ void __launch_bounds__(512, 4) k_main(
        const int* __restrict__ A, const float* __restrict__ s,
        const float* __restrict__ n, const float* __restrict__ nmaxp,
        const unsigned short* __restrict__ hThi, const unsigned short* __restrict__ hTlo,
        float* __restrict__ out) {
    __shared__ float lacc[8][16][64];   // 32 KB
    __shared__ float lz[8][16];

    const int tid = threadIdx.x;
    const int w  = tid >> 6;
    const int l  = tid & 63;
    const int lr = l & 15;
    const int lg = l >> 4;
    const int i0 = blockIdx.x * 16;

    const float sval = s[i0 + lr];
    const float tM = sval + nmaxp[0];
    const float Mv = fmaxf(tM, ALPHA * tM);
    float zacc = 0.0f;

    f32x4 acc0 = {0.f, 0.f, 0.f, 0.f}, acc1 = {0.f, 0.f, 0.f, 0.f};
    f32x4 acc2 = {0.f, 0.f, 0.f, 0.f}, acc3 = {0.f, 0.f, 0.f, 0.f};

    const int jbase = w * (N / 8);          // 1024 j per wave
    const int koff  = jbase + lg * 8;

    const int4*   Ap = (const int4*)(A + (size_t)(i0 + lr) * N + koff);
    const float4* np = (const float4*)(n + koff);
    const short8* b0h = (const short8*)(hThi + (size_t)(lr +  0) * N + koff);
    const short8* b1h = (const short8*)(hThi + (size_t)(lr + 16) * N + koff);
    const short8* b2h = (const short8*)(hThi + (size_t)(lr + 32) * N + koff);
    const short8* b3h = (const short8*)(hThi + (size_t)(lr + 48) * N + koff);
    const short8* b0l = (const short8*)(hTlo + (size_t)(lr +  0) * N + koff);
    const short8* b1l = (const short8*)(hTlo + (size_t)(lr + 16) * N + koff);
    const short8* b2l = (const short8*)(hTlo + (size_t)(lr + 32) * N + koff);
    const short8* b3l = (const short8*)(hTlo + (size_t)(lr + 48) * N + koff);

    // prefetch chunk 0
    int4 a0 = Ap[0], a1 = Ap[1];
    float4 nv0 = np[0], nv1 = np[1];

    for (int c = 0; c < 32; ++c) {
        // ---- prefetch next chunk's A and n (drain under e-phase + MFMA) ----
        const int pf = (c < 31) ? 8 : 0;
        int4 na0 = Ap[pf], na1 = Ap[pf + 1];
        float4 nn0 = np[pf], nn1 = np[pf + 1];

        // ---- B fragments for current chunk (L2-resident) ----
        short8 B0h = *b0h, B1h = *b1h, B2h = *b2h, B3h = *b3h;
        short8 B0l = *b0l, B1l = *b1l, B2l = *b2l, B3l = *b3l;

        // ---- e-phase: 8 e's per lane, packed straight into A-fragments ----
        int   av[8] = {a0.x, a0.y, a0.z, a0.w, a1.x, a1.y, a1.z, a1.w};
        float nf[8] = {nv0.x, nv0.y, nv0.z, nv0.w, nv1.x, nv1.y, nv1.z, nv1.w};
        short8 ahi = {}, alo = {};
#pragma unroll
        for (int j = 0; j < 8; ++j) {
            float t  = sval + nf[j];
            float lv = fmaxf(t, ALPHA * t);
            float ex = __expf(lv - Mv);
            ex = (av[j] != 0) ? ex : 0.0f;
            zacc += ex;
            unsigned xb = __float_as_uint(ex);
            ahi[j] = (short)(xb >> 16);
            float lof = ex - __uint_as_float(xb & 0xffff0000u);
            alo[j] = (short)(__float_as_uint(lof) >> 16);
        }

        // ---- 12 MFMAs: hi*hi + hi*lo + lo*hi ----
        acc0 = __builtin_amdgcn_mfma_f32_16x16x32_bf16(ahi, B0h, acc0, 0, 0, 0);
        acc1 = __builtin_amdgcn_mfma_f32_16x16x32_bf16(ahi, B1h, acc1, 0, 0, 0);
        acc2 = __builtin_amdgcn_mfma_f32_16x16x32_bf16(ahi, B2h, acc2, 0, 0, 0);
        acc3 = __builtin_amdgcn_mfma_f32_16x16x32_bf16(ahi, B3h, acc3, 0, 0, 0);
        acc0 = __builtin_amdgcn_mfma_f32_16x16x32_bf16(ahi, B0l, acc0, 0, 0, 0);
        acc1 = __builtin_amdgcn_mfma_f32_16x16x32_bf16(ahi, B1l, acc1, 0, 0, 0);
        acc2 = __builtin_amdgcn_mfma_f32_16x16x32_bf16(ahi, B2l, acc2, 0, 0, 0);
        acc3 = __builtin_amdgcn_mfma_f32_16x16x32_bf16(ahi, B3l, acc3, 0, 0, 0);
        acc0 = __builtin_amdgcn_mfma_f32_16x16x32_bf16(alo, B0h, acc0, 0, 0, 0);
        acc1 = __builtin_amdgcn_mfma_f32_16x16x32_bf16(alo, B1h, acc1, 0, 0, 0);
        acc2 = __builtin_amdgcn_mfma_f32_16x16x32_bf16(alo, B2h, acc2, 0, 0, 0);
        acc3 = __builtin_amdgcn_mfma_f32_16x16x32_bf16(alo, B3h, acc3, 0, 0, 0);

        // ---- rotate prefetch ----
        a0 = na0; a1 = na1; nv0 = nn0; nv1 = nn1;
        Ap += 8; np += 8;
        b0h += 4; b1h += 4; b2h += 4; b3h += 4;
        b0l += 4; b1l += 4; b2l += 4; b3l += 4;
    }

    // ---- z: sum the 4 k-groups holding the same row ----
    zacc += __shfl_xor(zacc, 16);
    zacc += __shfl_xor(zacc, 32);

    // ---- cross-wave combine ----
#pragma unroll
    for (int r = 0; r < 4; ++r) {
        lacc[w][lg * 4 + r][ 0 + lr] = acc0[r];
        lacc[w][lg * 4 + r][16 + lr] = acc1[r];
        lacc[w][lg * 4 + r][32 + lr] = acc2[r];
        lacc[w][lg * 4 + r][48 + lr] = acc3[r];
    }
    if (l < 16) lz[w][lr] = zacc;
    __syncthreads();

#pragma unroll
    for (int q = 0; q < 2; ++q) {
        int idx = tid + q * 512;
        int row = idx >> 6, col = idx & 63;
        float v = 0.0f, zz = 0.0f;
#pragma unroll
        for (int ww = 0; ww < 8; ++ww) {
            v  += lacc[ww][row][col];
            zz += lz[ww][row];
        }
        out[(size_t)(i0 + row) * NEWF + col] = fmaxf(v / zz, 0.0f);
    }
}

// ---------------------------------------------------------------------------
extern "C" void kernel_launch(void* const* d_in, const int* in_sizes, int n_in,
                              void* d_out, int out_size, void* d_ws, size_t ws_size,
                              hipStream_t stream) {
    const float* X       = (const float*)d_in[0];
    const int*   A       = (const int*)d_in[1];
    const float* W       = (const float*)d_in[2];
    const float* a_self  = (const float*)d_in[3];
    const float* a_neigh = (const float*)d_in[4];
    float* out = (float*)d_out;

    float* wsf = (float*)d_ws;
    float* h    = wsf;                        // N*NEWF         (524288 f)
    float* s    = h + (size_t)N * NEWF;       // N
    float* nv   = s + N;                      // N
    float* nmax = nv + N;                     // 1 (padded to 4)
    unsigned short* hThi = (unsigned short*)(nmax + 4);          // N*NEWF ushort
    unsigned short* hTlo = hThi + (size_t)N * NEWF;              // N*NEWF ushort

    k_hsn <<<N / 4,  256, 0, stream>>>(X, W, a_self, a_neigh, h, s, nv);
    k_tr  <<<N / 64, 256, 0, stream>>>(h, hThi, hTlo);
    k_nmax<<<1,     1024, 0, stream>>>(nv, nmax);
    k_main<<<N / 16, 512, 0, stream>>>(A, s, nv, nmax, hThi, hTlo, out);
}

// Round 4
// 432.089 us; speedup vs baseline: 2.1579x; 1.2634x over previous
//
#include <hip/hip_runtime.h>

#define N 8192
#define F 128
#define NEWF 64
#define ALPHA 0.2f
#define JSPLIT 8
#define JW (N / JSPLIT)     // 1024 j per block
#define NCH (JW / 32)       // 32 chunks of K=32
#define RB 64               // rows per block (4 waves x 16)

typedef float f32x4 __attribute__((ext_vector_type(4)));
typedef short short8 __attribute__((ext_vector_type(8)));

// ---------------------------------------------------------------------------
// Kernel 1: h = X @ W (f32), s = h @ a_self, n = h @ a_neigh
// ---------------------------------------------------------------------------
__global__ void k_hsn(const float* __restrict__ X, const float* __restrict__ W,
                      const float* __restrict__ a_self, const float* __restrict__ a_neigh,
                      float* __restrict__ h, float* __restrict__ s, float* __restrict__ n) {
    int row = blockIdx.x * 4 + (threadIdx.x >> 6);
    int l = threadIdx.x & 63;
    const float* xr = X + (size_t)row * F;
    float acc = 0.0f;
#pragma unroll 8
    for (int f = 0; f < F; ++f) acc += xr[f] * W[f * NEWF + l];
    h[(size_t)row * NEWF + l] = acc;
    float ts = acc * a_self[l];
    float tn = acc * a_neigh[l];
#pragma unroll
    for (int off = 32; off; off >>= 1) {
        ts += __shfl_xor(ts, off);
        tn += __shfl_xor(tn, off);
    }
    if (l == 0) { s[row] = ts; n[row] = tn; }
}

// ---------------------------------------------------------------------------
// Kernel 2: transpose h, split into bf16 hi/lo planes hT[c][j]
// ---------------------------------------------------------------------------
__global__ void k_tr(const float* __restrict__ h, unsigned short* __restrict__ hThi,
                     unsigned short* __restrict__ hTlo) {
    __shared__ float tile[64][65];
    const int t = threadIdx.x;
    const int j0 = blockIdx.x * 64;
    {
        const int jr = t >> 2, cs = (t & 3) * 16;
        const float4* src = (const float4*)(h + (size_t)(j0 + jr) * NEWF + cs);
#pragma unroll
        for (int q = 0; q < 4; ++q) {
            float4 v = src[q];
            tile[jr][cs + q * 4 + 0] = v.x; tile[jr][cs + q * 4 + 1] = v.y;
            tile[jr][cs + q * 4 + 2] = v.z; tile[jr][cs + q * 4 + 3] = v.w;
        }
    }
    __syncthreads();
    {
        const int c = t >> 2, js = (t & 3) * 16;
        short8 hi0 = {}, hi1 = {}, lo0 = {}, lo1 = {};
#pragma unroll
        for (int k = 0; k < 16; ++k) {
            float v = tile[js + k][c];
            unsigned xb = __float_as_uint(v);
            short hb = (short)(xb >> 16);
            float lof = v - __uint_as_float(xb & 0xffff0000u);
            short lb = (short)(__float_as_uint(lof) >> 16);
            if (k < 8) { hi0[k] = hb; lo0[k] = lb; }
            else       { hi1[k - 8] = hb; lo1[k - 8] = lb; }
        }
        size_t off = (size_t)c * N + j0 + js;
        *(short8*)(hThi + off)     = hi0;
        *(short8*)(hThi + off + 8) = hi1;
        *(short8*)(hTlo + off)     = lo0;
        *(short8*)(hTlo + off + 8) = lo1;
    }
}

// ---------------------------------------------------------------------------
// Kernel 3: nmax = max_j n[j]
// ---------------------------------------------------------------------------
__global__ void k_nmax(const float* __restrict__ n, float* __restrict__ nmax) {
    __shared__ float red[1024];
    int t = threadIdx.x;
    float4 v0 = ((const float4*)n)[t];
    float4 v1 = ((const float4*)n)[t + 1024];
    float m = fmaxf(fmaxf(fmaxf(v0.x, v0.y), fmaxf(v0.z, v0.w)),
                    fmaxf(fmaxf(v1.x, v1.y), fmaxf(v1.z, v1.w)));
    red[t] = m;
    __syncthreads();
    for (int off = 512; off; off >>= 1) {
        if (t < off) red[t] = fmaxf(red[t], red[t + off]);
        __syncthreads();
    }
    if (t == 0) nmax[0] = red[0];
}

// ---------------------------------------------------------------------------
// Kernel 4: fused attention, split-bf16 MFMA, B staged via double-buffered LDS.
//   Block = 256 thr (4 waves) = 64 rows; j-slice of 1024 per block (JSPLIT=8).
//   Per K=32 chunk: stage-next (global->reg, pinned early), e-phase in regs,
//   B frags from LDS, 12 MFMAs, reg->ds_write, lgkmcnt(0)+s_barrier (A-prefetch
//   stays in flight across the barrier). Partials to pacc/pz, no atomics.
// ---------------------------------------------------------------------------
__global__ void __launch_bounds__(256, 4) k_main(
        const int* __restrict__ A, const float* __restrict__ s,
        const float* __restrict__ n, const float* __restrict__ nmaxp,
        const unsigned short* __restrict__ hThi, const unsigned short* __restrict__ hTlo,
        float* __restrict__ pacc, float* __restrict__ pz) {
    __shared__ __align__(16) unsigned short bt[2][2][64][32];   // 16 KB dbuf B tiles

    const int tid = threadIdx.x;
    const int w = tid >> 6, l = tid & 63;
    const int lr = l & 15, lg = l >> 4;

    const int rb = blockIdx.x / JSPLIT;
    const int js = blockIdx.x % JSPLIT;
    const int r0 = rb * RB + w * 16;
    const int jb = js * JW;

    const float sval = s[r0 + lr];
    const float tM = sval + nmaxp[0];
    const float Mv = fmaxf(tM, ALPHA * tM);
    float zacc = 0.0f;

    f32x4 acc0 = {0.f,0.f,0.f,0.f}, acc1 = {0.f,0.f,0.f,0.f};
    f32x4 acc2 = {0.f,0.f,0.f,0.f}, acc3 = {0.f,0.f,0.f,0.f};

    // staging mapping: thread t stages row t>>2, j-sub (t&3)*8 (16B each plane)
    const int srow = tid >> 2, sj = (tid & 3) * 8;
    const short8* ghi = (const short8*)(hThi + (size_t)srow * N + jb + sj);
    const short8* glo = (const short8*)(hTlo + (size_t)srow * N + jb + sj);

    // ---- prologue: stage chunk 0 ----
    {
        short8 vhi = ghi[0];
        short8 vlo = glo[0];
        *(short8*)&bt[0][0][srow][sj] = vhi;
        *(short8*)&bt[0][1][srow][sj] = vlo;
    }
    asm volatile("s_waitcnt lgkmcnt(0)" ::: "memory");
    __builtin_amdgcn_s_barrier();

    const int4*   Ap  = (const int4*)(A + (size_t)(r0 + lr) * N + jb + lg * 8);
    const float4* npv = (const float4*)(n + jb + lg * 8);

    int4 a0 = Ap[0], a1 = Ap[1];
    float4 nv0 = npv[0], nv1 = npv[1];

    for (int c = 0; c < NCH; ++c) {
        const int p = c & 1;
        const int cn = (c + 1 < NCH) ? c + 1 : 0;   // wrap: dummy on last iter

        // ---- issue next-chunk loads FIRST, pin them with sched_barrier ----
        short8 nhi = ghi[cn * 4];
        short8 nlo = glo[cn * 4];
        int4   na0 = Ap[cn * 8], na1 = Ap[cn * 8 + 1];
        float4 nn0 = npv[cn * 8], nn1 = npv[cn * 8 + 1];
        __builtin_amdgcn_sched_barrier(0);

        // ---- e-phase: 8 e's per lane straight into A-fragments ----
        int   av[8] = {a0.x, a0.y, a0.z, a0.w, a1.x, a1.y, a1.z, a1.w};
        float nf[8] = {nv0.x, nv0.y, nv0.z, nv0.w, nv1.x, nv1.y, nv1.z, nv1.w};
        short8 ahi, alo;
#pragma unroll
        for (int j = 0; j < 8; ++j) {
            float t  = sval + nf[j];
            float lv = fmaxf(t, ALPHA * t);
            float ex = __expf(lv - Mv);
            ex = (av[j] != 0) ? ex : 0.0f;
            zacc += ex;
            unsigned xb = __float_as_uint(ex);
            ahi[j] = (short)(xb >> 16);
            float lof = ex - __uint_as_float(xb & 0xffff0000u);
            alo[j] = (short)(__float_as_uint(lof) >> 16);
        }

        // ---- B fragments from LDS (conflict-free b128) ----
        short8 B0h = *(const short8*)&bt[p][0][lr +  0][lg * 8];
        short8 B1h = *(const short8*)&bt[p][0][lr + 16][lg * 8];
        short8 B2h = *(const short8*)&bt[p][0][lr + 32][lg * 8];
        short8 B3h = *(const short8*)&bt[p][0][lr + 48][lg * 8];
        short8 B0l = *(const short8*)&bt[p][1][lr +  0][lg * 8];
        short8 B1l = *(const short8*)&bt[p][1][lr + 16][lg * 8];
        short8 B2l = *(const short8*)&bt[p][1][lr + 32][lg * 8];
        short8 B3l = *(const short8*)&bt[p][1][lr + 48][lg * 8];

        // ---- 12 MFMAs: hi*hi + hi*lo + lo*hi ----
        acc0 = __builtin_amdgcn_mfma_f32_16x16x32_bf16(ahi, B0h, acc0, 0, 0, 0);
        acc1 = __builtin_amdgcn_mfma_f32_16x16x32_bf16(ahi, B1h, acc1, 0, 0, 0);
        acc2 = __builtin_amdgcn_mfma_f32_16x16x32_bf16(ahi, B2h, acc2, 0, 0, 0);
        acc3 = __builtin_amdgcn_mfma_f32_16x16x32_bf16(ahi, B3h, acc3, 0, 0, 0);
        acc0 = __builtin_amdgcn_mfma_f32_16x16x32_bf16(ahi, B0l, acc0, 0, 0, 0);
        acc1 = __builtin_amdgcn_mfma_f32_16x16x32_bf16(ahi, B1l, acc1, 0, 0, 0);
        acc2 = __builtin_amdgcn_mfma_f32_16x16x32_bf16(ahi, B2l, acc2, 0, 0, 0);
        acc3 = __builtin_amdgcn_mfma_f32_16x16x32_bf16(ahi, B3l, acc3, 0, 0, 0);
        acc0 = __builtin_amdgcn_mfma_f32_16x16x32_bf16(alo, B0h, acc0, 0, 0, 0);
        acc1 = __builtin_amdgcn_mfma_f32_16x16x32_bf16(alo, B1h, acc1, 0, 0, 0);
        acc2 = __builtin_amdgcn_mfma_f32_16x16x32_bf16(alo, B2h, acc2, 0, 0, 0);
        acc3 = __builtin_amdgcn_mfma_f32_16x16x32_bf16(alo, B3h, acc3, 0, 0, 0);

        // ---- write next B tile, manual barrier (A-prefetch stays in flight) ----
        *(short8*)&bt[p ^ 1][0][srow][sj] = nhi;
        *(short8*)&bt[p ^ 1][1][srow][sj] = nlo;
        asm volatile("s_waitcnt lgkmcnt(0)" ::: "memory");
        __builtin_amdgcn_s_barrier();
        __builtin_amdgcn_sched_barrier(0);

        a0 = na0; a1 = na1; nv0 = nn0; nv1 = nn1;
    }

    // ---- z reduce over the 4 k-groups of each row ----
    zacc += __shfl_xor(zacc, 16);
    zacc += __shfl_xor(zacc, 32);

    // ---- write partials (each wave owns distinct rows; no cross-wave combine) ----
    float* pa = pacc + ((size_t)js * N + r0) * NEWF;
#pragma unroll
    for (int r = 0; r < 4; ++r) {
        int row = lg * 4 + r;
        pa[(size_t)row * NEWF +  0 + lr] = acc0[r];
        pa[(size_t)row * NEWF + 16 + lr] = acc1[r];
        pa[(size_t)row * NEWF + 32 + lr] = acc2[r];
        pa[(size_t)row * NEWF + 48 + lr] = acc3[r];
    }
    if (l < 16) pz[(size_t)js * N + r0 + lr] = zacc;
}

// ---------------------------------------------------------------------------
// Kernel 5: finalize — sum partials, divide, relu
// ---------------------------------------------------------------------------
__global__ void k_fin(const float* __restrict__ pacc, const float* __restrict__ pz,
                      float* __restrict__ out) {
    int t = blockIdx.x * 256 + threadIdx.x;     // 0 .. N*NEWF-1
    int i = t >> 6, k = t & 63;
    float v = 0.0f, z = 0.0f;
#pragma unroll
    for (int psl = 0; psl < JSPLIT; ++psl) {
        v += pacc[((size_t)psl * N + i) * NEWF + k];
        z += pz[(size_t)psl * N + i];
    }
    out[t] = fmaxf(v / z, 0.0f);
}

// ---------------------------------------------------------------------------
extern "C" void kernel_launch(void* const* d_in, const int* in_sizes, int n_in,
                              void* d_out, int out_size, void* d_ws, size_t ws_size,
                              hipStream_t stream) {
    const float* X       = (const float*)d_in[0];
    const int*   A       = (const int*)d_in[1];
    const float* W       = (const float*)d_in[2];
    const float* a_self  = (const float*)d_in[3];
    const float* a_neigh = (const float*)d_in[4];
    float* out = (float*)d_out;

    float* wsf = (float*)d_ws;
    float* h    = wsf;                        // N*NEWF f32
    float* s    = h + (size_t)N * NEWF;       // N
    float* nv   = s + N;                      // N
    float* nmax = nv + N;                     // 4
    unsigned short* hThi = (unsigned short*)(nmax + 4);   // N*NEWF ushort (1MB)
    unsigned short* hTlo = hThi + (size_t)N * NEWF;       // N*NEWF ushort (1MB)
    float* pacc = (float*)(hTlo + (size_t)N * NEWF);      // JSPLIT*N*NEWF f32 (16MB)
    float* pz   = pacc + (size_t)JSPLIT * N * NEWF;       // JSPLIT*N f32 (256KB)

    k_hsn <<<N / 4,        256, 0, stream>>>(X, W, a_self, a_neigh, h, s, nv);
    k_tr  <<<N / 64,       256, 0, stream>>>(h, hThi, hTlo);
    k_nmax<<<1,           1024, 0, stream>>>(nv, nmax);
    k_main<<<(N / RB) * JSPLIT, 256, 0, stream>>>(A, s, nv, nmax, hThi, hTlo, pacc, pz);
    k_fin <<<(N * NEWF) / 256, 256, 0, stream>>>(pacc, pz, out);
}